// Round 7
// baseline (435.447 us; speedup 1.0000x reference)
//
#include <hip/hip_runtime.h>
#include <math.h>

#define BB 4
#define SS 1024
#define DD 1024
#define HH 16
#define HDD 64
#define MTOT (BB*SS)   // 4096
#define MB (1024*1024)

typedef float  f32x4  __attribute__((ext_vector_type(4)));
typedef __bf16 bf16x8 __attribute__((ext_vector_type(8)));
typedef unsigned short u16;

__device__ __forceinline__ unsigned short f2bf(float f) {
    union { float f; unsigned u; } v; v.f = f;
    unsigned r = v.u + 0x7FFFu + ((v.u >> 16) & 1u);
    return (unsigned short)(r >> 16);
}
__device__ __forceinline__ float bf2f(unsigned short u) {
    union { unsigned u; float f; } v; v.u = ((unsigned)u) << 16;
    return v.f;
}
__device__ __forceinline__ f32x4 mfma16(bf16x8 a, bf16x8 b, f32x4 c) {
    return __builtin_amdgcn_mfma_f32_16x16x32_bf16(a, b, c, 0, 0, 0);
}
__device__ __forceinline__ void gload16(const void* g, void* l) {
    __builtin_amdgcn_global_load_lds(
        (const __attribute__((address_space(1))) void*)g,
        (__attribute__((address_space(3))) void*)l, 16, 0, 0);
}

// ---------------- split: fp32 -> bf16 hi/lo ----------------
__global__ void split_kernel(const float* __restrict__ in, u16* __restrict__ hi,
                             u16* __restrict__ lo, int n4)
{
    for (int i = blockIdx.x*blockDim.x + threadIdx.x; i < n4; i += gridDim.x*blockDim.x) {
        f32x4 v = ((const f32x4*)in)[i];
        ushort4 h4, l4;
        h4.x = f2bf(v[0]); l4.x = f2bf(v[0] - bf2f(h4.x));
        h4.y = f2bf(v[1]); l4.y = f2bf(v[1] - bf2f(h4.y));
        h4.z = f2bf(v[2]); l4.z = f2bf(v[2] - bf2f(h4.z));
        h4.w = f2bf(v[3]); l4.w = f2bf(v[3] - bf2f(h4.w));
        ((ushort4*)hi)[i] = h4; ((ushort4*)lo)[i] = l4;
    }
}

// ------- fused transpose+split for all 5 weights: W[k][n] -> WT hi (+opt lo) [n][k] -------
__global__ __launch_bounds__(256)
void tsplit5_kernel(const float* W0, u16* h0,
                    const float* W1, u16* h1,
                    const float* W2, u16* h2,
                    const float* W3, u16* h3,
                    const float* W4, u16* h4, u16* l4T)
{
    const float* W; u16* hT; u16* lT = nullptr;
    switch (blockIdx.z) {
        case 0: W = W0; hT = h0; break;
        case 1: W = W1; hT = h1; break;
        case 2: W = W2; hT = h2; break;
        case 3: W = W3; hT = h3; break;
        default: W = W4; hT = h4; lT = l4T; break;
    }
    __shared__ float tile[64][65];
    const int t  = threadIdx.x;
    const int k0 = blockIdx.y * 64, n0 = blockIdx.x * 64;
    const int r  = t >> 4, c4 = (t & 15) * 4;
    #pragma unroll
    for (int rr = 0; rr < 4; ++rr) {
        const int k = r + rr*16;
        f32x4 v = *(const f32x4*)&W[(size_t)(k0 + k)*1024 + n0 + c4];
        tile[k][c4+0] = v[0]; tile[k][c4+1] = v[1]; tile[k][c4+2] = v[2]; tile[k][c4+3] = v[3];
    }
    __syncthreads();
    #pragma unroll
    for (int rr = 0; rr < 4; ++rr) {
        const int nl = r + rr*16;
        ushort4 hh, ll;
        {
            float v;
            v = tile[c4+0][nl]; hh.x = f2bf(v); ll.x = f2bf(v - bf2f(hh.x));
            v = tile[c4+1][nl]; hh.y = f2bf(v); ll.y = f2bf(v - bf2f(hh.y));
            v = tile[c4+2][nl]; hh.z = f2bf(v); ll.z = f2bf(v - bf2f(hh.z));
            v = tile[c4+3][nl]; hh.w = f2bf(v); ll.w = f2bf(v - bf2f(hh.w));
        }
        *(ushort4*)&hT[(size_t)(n0 + nl)*1024 + k0 + c4] = hh;
        if (lT) *(ushort4*)&lT[(size_t)(n0 + nl)*1024 + k0 + c4] = ll;
    }
}

// ---------------- trust-affinity rank-1 constants ----------------
__global__ void tconst_kernel(const float* __restrict__ Wtp, const float* __restrict__ btp,
                              float* __restrict__ out3)
{
    const int l = threadIdx.x;   // 64 threads
    const float w = Wtp[l], b = btp[l];
    float a = w*w, m = w*b, c = b*b;
    #pragma unroll
    for (int s = 32; s; s >>= 1) {
        a += __shfl_down(a, s);
        m += __shfl_down(m, s);
        c += __shfl_down(c, s);
    }
    if (l == 0) { out3[0] = a; out3[1] = m; out3[2] = c; }
}

// ---------------- trust bias table: T[b][q][k] = bf16(0.1*sigmoid(ta)) ----------------
__global__ __launch_bounds__(256)
void tbias_kernel(const float* __restrict__ trust, const float* __restrict__ tconst,
                  u16* __restrict__ T)
{
    const int b = blockIdx.y;
    const int q = blockIdx.x;
    const float tq = trust[b*SS + q];
    const float c1 = tconst[0], c2 = tconst[1], c3 = tconst[2];
    const int k0 = threadIdx.x * 4;
    f32x4 tk = *(const f32x4*)&trust[b*SS + k0];
    ushort4 o;
    #pragma unroll
    for (int j = 0; j < 4; ++j) {
        const float ta = c1*tq*tk[j] + c2*(tq + tk[j]) + c3;
        const float v  = 0.1f/(1.f + __expf(-ta));
        ((u16*)&o)[j] = f2bf(v);
    }
    *(ushort4*)&T[((size_t)b*SS + q)*SS + k0] = o;
}

// ---------------- split-bf16 MFMA GEMM ----------------
// PASSES=3: AhBh + AhBl + AlBh ; PASSES=2: AhBh + AlBh ; PASSES=1: AhBh
template<int MODE, int PASSES>
__global__ __launch_bounds__(256)
void mgemm(const u16* __restrict__ Ah, const u16* __restrict__ Al,
           const u16* __restrict__ Bh, const u16* __restrict__ Bl,
           const float* __restrict__ bias,
           float* __restrict__ outF, u16* __restrict__ outH, u16* __restrict__ outL,
           int M, int N,
           const float* __restrict__ trust, const float* __restrict__ wlast,
           const u16* __restrict__ attH, const u16* __restrict__ attL)
{
    constexpr int NT   = (PASSES == 3) ? 4 : (PASSES == 2) ? 3 : 2;
    constexpr int BIDX = (PASSES == 1) ? 1 : 2;
    __shared__ u16 lds[2][NT][128*64];

    const int t    = threadIdx.x;
    const int lane = t & 63, wave = t >> 6;
    const int l15  = lane & 15, l4 = lane >> 4;
    const int wr   = wave >> 1, wc = wave & 1;
    const int w64  = wave << 6;
    const int m0   = blockIdx.y * 128, n0 = blockIdx.x * 128;

    const u16* srcs[NT];
    srcs[0] = Ah + (size_t)m0*1024;
    if (PASSES >= 2) srcs[1] = Al + (size_t)m0*1024;
    srcs[BIDX] = Bh + (size_t)n0*1024;
    if (PASSES == 3) srcs[3] = Bl + (size_t)n0*1024;

    f32x4 acc[4][4];
    #pragma unroll
    for (int i = 0; i < 4; ++i)
        #pragma unroll
        for (int j = 0; j < 4; ++j) acc[i][j] = (f32x4){0.f,0.f,0.f,0.f};

#define STAGE(BUF, KOFF) do {                                                  \
    _Pragma("unroll")                                                          \
    for (int tl_ = 0; tl_ < NT; ++tl_) {                                       \
        _Pragma("unroll")                                                      \
        for (int it_ = 0; it_ < 4; ++it_) {                                    \
            const int idx_ = it_*256 + t;                                      \
            const int row_ = idx_ >> 3;                                        \
            const int c_   = (idx_ & 7) ^ (row_ & 7);                          \
            gload16(srcs[tl_] + (KOFF) + (size_t)row_*1024 + c_*8,             \
                    &lds[BUF][tl_][(it_*256 + w64)*8]);                        \
        }                                                                      \
    }                                                                          \
} while(0)

#define COMPUTE(BUF) do {                                                      \
    _Pragma("unroll")                                                          \
    for (int kk_ = 0; kk_ < 2; ++kk_) {                                        \
        const int cb_ = (kk_<<2) + l4;                                         \
        bf16x8 ah_[4], al_[4];                                                 \
        _Pragma("unroll")                                                      \
        for (int i_ = 0; i_ < 4; ++i_) {                                       \
            const int row_ = (wr<<6) + (i_<<4) + l15;                          \
            const int off_ = (row_<<6) + ((cb_ ^ (row_&7)) << 3);              \
            ah_[i_] = *(const bf16x8*)&lds[BUF][0][off_];                      \
            if (PASSES >= 2) al_[i_] = *(const bf16x8*)&lds[BUF][1][off_];     \
        }                                                                      \
        _Pragma("unroll")                                                      \
        for (int j_ = 0; j_ < 4; ++j_) {                                       \
            const int row_ = (wc<<6) + (j_<<4) + l15;                          \
            const int off_ = (row_<<6) + ((cb_ ^ (row_&7)) << 3);              \
            bf16x8 bh_ = *(const bf16x8*)&lds[BUF][BIDX][off_];                \
            bf16x8 bl_;                                                        \
            if (PASSES == 3) bl_ = *(const bf16x8*)&lds[BUF][3][off_];         \
            _Pragma("unroll")                                                  \
            for (int i_ = 0; i_ < 4; ++i_) {                                   \
                acc[i_][j_] = mfma16(ah_[i_], bh_, acc[i_][j_]);               \
                if (PASSES == 3) acc[i_][j_] = mfma16(ah_[i_], bl_, acc[i_][j_]); \
                if (PASSES >= 2) acc[i_][j_] = mfma16(al_[i_], bh_, acc[i_][j_]); \
            }                                                                  \
        }                                                                      \
    }                                                                          \
} while(0)

    STAGE(0, 0);
    __syncthreads();
    int cur = 0;
    for (int s = 0; s < 15; ++s) {
        if (cur == 0) STAGE(1, (s+1)*64);
        else          STAGE(0, (s+1)*64);
        COMPUTE(cur);
        __syncthreads();
        cur ^= 1;
    }
    COMPUTE(cur);
#undef STAGE
#undef COMPUTE

    // ---- epilogue ----
    #pragma unroll
    for (int i = 0; i < 4; ++i)
        #pragma unroll
        for (int j = 0; j < 4; ++j)
            #pragma unroll
            for (int r = 0; r < 4; ++r) {
                const int m = m0 + (wr<<6) + (i<<4) + (l4<<2) + r;
                const int n = n0 + (wc<<6) + (j<<4) + l15;
                const float v = acc[i][j][r];
                if (MODE == 0) {
                    outF[(size_t)m*N + n] = v + bias[n];
                } else if (MODE == 2) {
                    outH[(size_t)m*N + n] = f2bf(v + bias[n]);
                } else if (MODE == 3) {
                    outH[(size_t)m*N + n] = f2bf(v + bias[m]);
                } else {
                    const float pre = v + bias[n] + trust[m]*wlast[n];
                    const float g = 1.f/(1.f + __expf(-pre));
                    const float att = bf2f(attH[(size_t)m*N + n]) + bf2f(attL[(size_t)m*N + n]);
                    const float gated = att*g;
                    const unsigned short hb = f2bf(gated);
                    outH[(size_t)m*N + n] = hb;
                    outL[(size_t)m*N + n] = f2bf(gated - bf2f(hb));
                }
            }
}

// ---------------- Attention v4: half-strip LDS (33 KB) for 3-4 blocks/CU ----------------
// Block: 16 q rows x (b,h), 512 threads / 8 waves; wave w owns keys [w*128, w*128+128).
// S/P lives in registers; P staged to a 32KB fp32 half-strip twice (waves 0-3, then 4-7);
// attn write + PV split into the two corresponding phases.
__global__ __launch_bounds__(512, 6)
void attn_kernel(const u16* __restrict__ Qb, const u16* __restrict__ Kb,
                 const u16* __restrict__ Vt, const u16* __restrict__ T,
                 const int* __restrict__ mask,
                 float* __restrict__ attnOut, u16* __restrict__ attH, u16* __restrict__ attL)
{
    __shared__ float P[16*512];       // 32 KB half-strip (aliased for O reduce at the end)
    __shared__ float redA[8][16];
    __shared__ float redB[8][16];
    __shared__ int   mqv[16];

    const int t    = threadIdx.x;
    const int lane = t & 63, wave = t >> 6;     // 8 waves
    const int l15  = lane & 15, l4 = lane >> 4;
    const int q0   = blockIdx.x * 16, h = blockIdx.y, b = blockIdx.z;
    const int wk0  = wave * 128;

    if (t < 16) mqv[t] = mask[b*SS + q0 + t];

    const u16* Qp = Qb + ((size_t)(b*SS + q0 + l15))*DD + h*HDD + l4*8;
    bf16x8 qf0 = *(const bf16x8*)Qp;
    bf16x8 qf1 = *(const bf16x8*)(Qp + 32);

    const u16* Tbase = T + ((size_t)b*SS + q0 + l4*4)*SS + wk0 + l15;
    __syncthreads();

    // ---- QK^T: 8 key tiles of 16 per wave ----
    f32x4 sacc[8];
    #pragma unroll
    for (int tt = 0; tt < 8; ++tt) sacc[tt] = (f32x4){0.f,0.f,0.f,0.f};

    const u16* Kbase = Kb + ((size_t)(b*SS + wk0 + l15))*DD + h*HDD + l4*8;
    #pragma unroll
    for (int tt = 0; tt < 8; ++tt) {
        const u16* Kp = Kbase + (size_t)tt*(16*DD);
        bf16x8 kf0 = *(const bf16x8*)Kp;
        bf16x8 kf1 = *(const bf16x8*)(Kp + 32);
        sacc[tt] = mfma16(qf0, kf0, sacc[tt]);
        sacc[tt] = mfma16(qf1, kf1, sacc[tt]);
    }

    // ---- bias + mask + wave-local row-max ----
    int mrow[4];
    #pragma unroll
    for (int r = 0; r < 4; ++r) mrow[r] = mqv[l4*4 + r];

    float mx[4] = {-3e38f, -3e38f, -3e38f, -3e38f};
    #pragma unroll
    for (int tt = 0; tt < 8; ++tt) {
        #pragma unroll
        for (int r = 0; r < 4; ++r) {
            const float bias = bf2f(Tbase[(size_t)r*SS + tt*16]);
            float s = sacc[tt][r]*0.125f + bias;
            s = mrow[r] ? s : -1e9f;
            sacc[tt][r] = s;
            mx[r] = fmaxf(mx[r], s);
        }
    }
    #pragma unroll
    for (int r = 0; r < 4; ++r)
        #pragma unroll
        for (int xm = 1; xm < 16; xm <<= 1) mx[r] = fmaxf(mx[r], __shfl_xor(mx[r], xm));
    if (l15 == 0) {
        #pragma unroll
        for (int r = 0; r < 4; ++r) redA[wave][l4*4 + r] = mx[r];
    }
    __syncthreads();

    float mxa[4];
    #pragma unroll
    for (int r = 0; r < 4; ++r) {
        const int row = l4*4 + r;
        float m = redA[0][row];
        #pragma unroll
        for (int w = 1; w < 8; ++w) m = fmaxf(m, redA[w][row]);
        mxa[r] = m;
    }

    // ---- exp in regs + row-sum (no LDS store yet) ----
    float sum[4] = {0.f, 0.f, 0.f, 0.f};
    #pragma unroll
    for (int tt = 0; tt < 8; ++tt)
        #pragma unroll
        for (int r = 0; r < 4; ++r) {
            const float p = __expf(sacc[tt][r] - mxa[r]);
            sacc[tt][r] = p;
            sum[r] += p;
        }
    #pragma unroll
    for (int r = 0; r < 4; ++r)
        #pragma unroll
        for (int xm = 1; xm < 16; xm <<= 1) sum[r] += __shfl_xor(sum[r], xm);
    if (l15 == 0) {
        #pragma unroll
        for (int r = 0; r < 4; ++r) redB[wave][l4*4 + r] = sum[r];
    }
    __syncthreads();

    // row inverse sums
    float inv4[4];
    #pragma unroll
    for (int r = 0; r < 4; ++r) {
        const int row = l4*4 + r;
        float s8 = 0.f;
        #pragma unroll
        for (int w = 0; w < 8; ++w) s8 += redB[w][row];
        inv4[r] = 1.f / s8;
    }
    const int wrow = t >> 5;              // attn-write row (16 rows, 32 threads each)
    const int wcl  = t & 31;
    float wiv;
    {
        float s8 = 0.f;
        #pragma unroll
        for (int w = 0; w < 8; ++w) s8 += redB[w][wrow];
        wiv = 1.f / s8;
    }
    float* gRow = attnOut + ((size_t)(b*HH + h))*SS*SS + (size_t)(q0 + wrow)*SS;

    const u16* Vbase = Vt + ((size_t)(h*HDD + l15))*MTOT + b*SS + wk0 + l4*8;
    f32x4 pv[4];
    #pragma unroll
    for (int nt = 0; nt < 4; ++nt) pv[nt] = (f32x4){0.f,0.f,0.f,0.f};

    // ================= two half-strip phases =================
    #pragma unroll
    for (int ph = 0; ph < 2; ++ph) {
        // store this half's P (waves [4*ph, 4*ph+4))
        if ((wave >> 2) == ph) {
            #pragma unroll
            for (int tt = 0; tt < 8; ++tt) {
                const int kk = (wk0 - ph*512) + tt*16 + l15;
                const int c = kk >> 2, j = kk & 3;
                #pragma unroll
                for (int r = 0; r < 4; ++r) {
                    const int row = l4*4 + r;
                    P[row*512 + ((c ^ (row & 7)) << 2) + j] = sacc[tt][r];
                }
            }
        }
        __syncthreads();

        // stream attn cols [512*ph, 512*ph+512) (all threads, coalesced f32x4)
        #pragma unroll
        for (int i = 0; i < 4; ++i) {
            const int c = wcl + i*32;     // chunk 0..127
            f32x4 v = *(f32x4*)&P[wrow*512 + ((c ^ (wrow & 7)) << 2)];
            v *= wiv;
            *(f32x4*)&gRow[ph*512 + c*4] = v;
        }

        // PV for this half's waves (their own 128-key strip)
        if ((wave >> 2) == ph) {
            #pragma unroll
            for (int t2 = 0; t2 < 4; ++t2) {
                const int kk = (wk0 - ph*512) + t2*32 + l4*8;
                const int c0 = kk >> 2;
                f32x4 a0 = *(f32x4*)&P[l15*512 + (((c0    ) ^ (l15 & 7)) << 2)];
                f32x4 a1 = *(f32x4*)&P[l15*512 + (((c0 + 1) ^ (l15 & 7)) << 2)];
                bf16x8 af;
                af[0] = (__bf16)a0[0]; af[1] = (__bf16)a0[1]; af[2] = (__bf16)a0[2]; af[3] = (__bf16)a0[3];
                af[4] = (__bf16)a1[0]; af[5] = (__bf16)a1[1]; af[6] = (__bf16)a1[2]; af[7] = (__bf16)a1[3];
                #pragma unroll
                for (int nt = 0; nt < 4; ++nt) {
                    bf16x8 bf = *(const bf16x8*)(Vbase + (size_t)nt*16*MTOT + t2*32);
                    pv[nt] = mfma16(af, bf, pv[nt]);
                }
            }
        }
        __syncthreads();   // half consumed before overwrite / final alias
    }

    // ---- cross-wave reduce through LDS (alias P = 8192 floats), scaled by 1/sum ----
    float* pw = P + wave*1024;
    #pragma unroll
    for (int nt = 0; nt < 4; ++nt)
        #pragma unroll
        for (int r = 0; r < 4; ++r)
            pw[(l4*4 + r)*64 + nt*16 + l15] = pv[nt][r] * inv4[r];
    __syncthreads();

    {
        const int q = t >> 5, d0 = (t & 31)*2;
        float sx = 0.f, sy = 0.f;
        #pragma unroll
        for (int w = 0; w < 8; ++w) {
            float2 v = *(float2*)&P[w*1024 + q*64 + d0];
            sx += v.x; sy += v.y;
        }
        const size_t off = ((size_t)(b*SS + q0 + q))*DD + h*HDD + d0;
        const unsigned short h0 = f2bf(sx), h1 = f2bf(sy);
        ushort2 hh = {h0, h1};
        ushort2 ll = {f2bf(sx - bf2f(h0)), f2bf(sy - bf2f(h1))};
        *(ushort2*)&attH[off] = hh;
        *(ushort2*)&attL[off] = ll;
    }
}

extern "C" void kernel_launch(void* const* d_in, const int* in_sizes, int n_in,
                              void* d_out, int out_size, void* d_ws, size_t ws_size,
                              hipStream_t stream) {
    const float* x     = (const float*)d_in[0];
    const float* trust = (const float*)d_in[1];
    const int*   mask  = (const int*)  d_in[2];
    const float* Wq    = (const float*)d_in[3];
    const float* bq    = (const float*)d_in[4];
    const float* Wk    = (const float*)d_in[5];
    const float* bk    = (const float*)d_in[6];
    const float* Wv    = (const float*)d_in[7];
    const float* bv    = (const float*)d_in[8];
    const float* Wtp   = (const float*)d_in[9];
    const float* btp   = (const float*)d_in[10];
    const float* Wg    = (const float*)d_in[11];
    const float* bg    = (const float*)d_in[12];
    const float* Wo    = (const float*)d_in[13];
    const float* bo    = (const float*)d_in[14];

    float* out     = (float*)d_out;
    float* attnOut = out + (size_t)MTOT * DD;

    char* ws = (char*)d_ws;
    u16* xh   = (u16*)(ws + (size_t)0*MB);    // 8 MB -> attH later
    u16* xl   = (u16*)(ws + (size_t)8*MB);    // 8 MB -> attL later
    u16* WqTh = (u16*)(ws + (size_t)16*MB);
    u16* WkTh = (u16*)(ws + (size_t)18*MB);
    u16* WvTh = (u16*)(ws + (size_t)20*MB);
    u16* WgTh = (u16*)(ws + (size_t)22*MB);
    u16* WoTh = (u16*)(ws + (size_t)24*MB);
    u16* WoTl = (u16*)(ws + (size_t)26*MB);
    u16* Qbf  = (u16*)(ws + (size_t)28*MB);   // 8 MB -> Gh later
    u16* Kbf  = (u16*)(ws + (size_t)36*MB);   // 8 MB -> Gl later
    u16* Vt   = (u16*)(ws + (size_t)44*MB);   // 8 MB
    u16* Tb   = (u16*)(ws + (size_t)52*MB);   // 8 MB bf16 trust-bias table
    float* tconst = (float*)(ws + (size_t)60*MB);
    u16* attH = xh;
    u16* attL = xl;
    u16* Gh   = Qbf;
    u16* Gl   = Kbf;

    const dim3 blk(256);

    tconst_kernel<<<1, 64, 0, stream>>>(Wtp, btp, tconst);
    tbias_kernel<<<dim3(SS, BB), blk, 0, stream>>>(trust, tconst, Tb);
    split_kernel<<<2048, blk, 0, stream>>>(x, xh, xl, MTOT*DD/4);
    tsplit5_kernel<<<dim3(16, 16, 5), blk, 0, stream>>>(
        Wq, WqTh, Wk, WkTh, Wv, WvTh, Wg, WgTh, Wo, WoTh, WoTl);

    // Q, K: 2-pass (AhBh + AlBh), bf16 out
    mgemm<2,2><<<dim3(DD/128, MTOT/128), blk, 0, stream>>>(
        xh, xl, WqTh, nullptr, bq, nullptr, Qbf, nullptr, MTOT, DD,
        nullptr, nullptr, nullptr, nullptr);
    mgemm<2,2><<<dim3(DD/128, MTOT/128), blk, 0, stream>>>(
        xh, xl, WkTh, nullptr, bk, nullptr, Kbf, nullptr, MTOT, DD,
        nullptr, nullptr, nullptr, nullptr);
    // V^T: 1-pass, C[d_glob][m] = WvT @ x^T (bias by row)
    mgemm<3,1><<<dim3(MTOT/128, DD/128), blk, 0, stream>>>(
        WvTh, nullptr, xh, nullptr, bv, nullptr, Vt, nullptr, DD, MTOT,
        nullptr, nullptr, nullptr, nullptr);

    attn_kernel<<<dim3(SS/16, HH, BB), dim3(512), 0, stream>>>(
        Qbf, Kbf, Vt, Tb, mask, attnOut, attH, attL);

    // gate: 1-pass; gated = attended * sigmoid(attended@Wg[0:1024] + bg + trust*wlast)
    mgemm<1,1><<<dim3(DD/128, MTOT/128), blk, 0, stream>>>(
        attH, nullptr, WgTh, nullptr, bg, nullptr, Gh, Gl, MTOT, DD,
        trust, Wg + (size_t)DD*DD, attH, attL);
    // out = gated @ Wo + bo (fp32, 3-pass)
    mgemm<0,3><<<dim3(DD/128, MTOT/128), blk, 0, stream>>>(
        Gh, Gl, WoTh, WoTl, bo, out, nullptr, nullptr, MTOT, DD,
        nullptr, nullptr, nullptr, nullptr);
}

// Round 8
// 339.695 us; speedup vs baseline: 1.2819x; 1.2819x over previous
//
#include <hip/hip_runtime.h>
#include <math.h>

#define BB 4
#define SS 1024
#define DD 1024
#define HH 16
#define HDD 64
#define MTOT (BB*SS)   // 4096
#define MB (1024*1024)

typedef float  f32x4  __attribute__((ext_vector_type(4)));
typedef __bf16 bf16x8 __attribute__((ext_vector_type(8)));
typedef unsigned short u16;

__device__ __forceinline__ unsigned short f2bf(float f) {
    union { float f; unsigned u; } v; v.f = f;
    unsigned r = v.u + 0x7FFFu + ((v.u >> 16) & 1u);
    return (unsigned short)(r >> 16);
}
__device__ __forceinline__ float bf2f(unsigned short u) {
    union { unsigned u; float f; } v; v.u = ((unsigned)u) << 16;
    return v.f;
}
__device__ __forceinline__ f32x4 mfma16(bf16x8 a, bf16x8 b, f32x4 c) {
    return __builtin_amdgcn_mfma_f32_16x16x32_bf16(a, b, c, 0, 0, 0);
}
__device__ __forceinline__ void gload16(const void* g, void* l) {
    __builtin_amdgcn_global_load_lds(
        (const __attribute__((address_space(1))) void*)g,
        (__attribute__((address_space(3))) void*)l, 16, 0, 0);
}

// ---------------- split: fp32 -> bf16 hi/lo ----------------
__global__ void split_kernel(const float* __restrict__ in, u16* __restrict__ hi,
                             u16* __restrict__ lo, int n4)
{
    for (int i = blockIdx.x*blockDim.x + threadIdx.x; i < n4; i += gridDim.x*blockDim.x) {
        f32x4 v = ((const f32x4*)in)[i];
        ushort4 h4, l4;
        h4.x = f2bf(v[0]); l4.x = f2bf(v[0] - bf2f(h4.x));
        h4.y = f2bf(v[1]); l4.y = f2bf(v[1] - bf2f(h4.y));
        h4.z = f2bf(v[2]); l4.z = f2bf(v[2] - bf2f(h4.z));
        h4.w = f2bf(v[3]); l4.w = f2bf(v[3] - bf2f(h4.w));
        ((ushort4*)hi)[i] = h4; ((ushort4*)lo)[i] = l4;
    }
}

// ------- fused transpose+split for all 5 weights: W[k][n] -> WT hi (+opt lo) [n][k] -------
__global__ __launch_bounds__(256)
void tsplit5_kernel(const float* W0, u16* h0,
                    const float* W1, u16* h1,
                    const float* W2, u16* h2,
                    const float* W3, u16* h3,
                    const float* W4, u16* h4, u16* l4T)
{
    const float* W; u16* hT; u16* lT = nullptr;
    switch (blockIdx.z) {
        case 0: W = W0; hT = h0; break;
        case 1: W = W1; hT = h1; break;
        case 2: W = W2; hT = h2; break;
        case 3: W = W3; hT = h3; break;
        default: W = W4; hT = h4; lT = l4T; break;
    }
    __shared__ float tile[64][65];
    const int t  = threadIdx.x;
    const int k0 = blockIdx.y * 64, n0 = blockIdx.x * 64;
    const int r  = t >> 4, c4 = (t & 15) * 4;
    #pragma unroll
    for (int rr = 0; rr < 4; ++rr) {
        const int k = r + rr*16;
        f32x4 v = *(const f32x4*)&W[(size_t)(k0 + k)*1024 + n0 + c4];
        tile[k][c4+0] = v[0]; tile[k][c4+1] = v[1]; tile[k][c4+2] = v[2]; tile[k][c4+3] = v[3];
    }
    __syncthreads();
    #pragma unroll
    for (int rr = 0; rr < 4; ++rr) {
        const int nl = r + rr*16;
        ushort4 hh, ll;
        {
            float v;
            v = tile[c4+0][nl]; hh.x = f2bf(v); ll.x = f2bf(v - bf2f(hh.x));
            v = tile[c4+1][nl]; hh.y = f2bf(v); ll.y = f2bf(v - bf2f(hh.y));
            v = tile[c4+2][nl]; hh.z = f2bf(v); ll.z = f2bf(v - bf2f(hh.z));
            v = tile[c4+3][nl]; hh.w = f2bf(v); ll.w = f2bf(v - bf2f(hh.w));
        }
        *(ushort4*)&hT[(size_t)(n0 + nl)*1024 + k0 + c4] = hh;
        if (lT) *(ushort4*)&lT[(size_t)(n0 + nl)*1024 + k0 + c4] = ll;
    }
}

// ---------------- trust-affinity rank-1 constants ----------------
__global__ void tconst_kernel(const float* __restrict__ Wtp, const float* __restrict__ btp,
                              float* __restrict__ out3)
{
    const int l = threadIdx.x;   // 64 threads
    const float w = Wtp[l], b = btp[l];
    float a = w*w, m = w*b, c = b*b;
    #pragma unroll
    for (int s = 32; s; s >>= 1) {
        a += __shfl_down(a, s);
        m += __shfl_down(m, s);
        c += __shfl_down(c, s);
    }
    if (l == 0) { out3[0] = a; out3[1] = m; out3[2] = c; }
}

// ---------------- trust bias table: T[b][q][k] = bf16(0.1*sigmoid(ta)) ----------------
__global__ __launch_bounds__(256)
void tbias_kernel(const float* __restrict__ trust, const float* __restrict__ tconst,
                  u16* __restrict__ T)
{
    const int b = blockIdx.y;
    const int q = blockIdx.x;
    const float tq = trust[b*SS + q];
    const float c1 = tconst[0], c2 = tconst[1], c3 = tconst[2];
    const int k0 = threadIdx.x * 4;
    f32x4 tk = *(const f32x4*)&trust[b*SS + k0];
    ushort4 o;
    #pragma unroll
    for (int j = 0; j < 4; ++j) {
        const float ta = c1*tq*tk[j] + c2*(tq + tk[j]) + c3;
        const float v  = 0.1f/(1.f + __expf(-ta));
        ((u16*)&o)[j] = f2bf(v);
    }
    *(ushort4*)&T[((size_t)b*SS + q)*SS + k0] = o;
}

// ---------------- split-bf16 MFMA GEMM ----------------
// PASSES=3: AhBh + AhBl + AlBh ; PASSES=2: AhBh + AlBh ; PASSES=1: AhBh
template<int MODE, int PASSES>
__global__ __launch_bounds__(256)
void mgemm(const u16* __restrict__ Ah, const u16* __restrict__ Al,
           const u16* __restrict__ Bh, const u16* __restrict__ Bl,
           const float* __restrict__ bias,
           float* __restrict__ outF, u16* __restrict__ outH, u16* __restrict__ outL,
           int M, int N,
           const float* __restrict__ trust, const float* __restrict__ wlast,
           const u16* __restrict__ attH, const u16* __restrict__ attL)
{
    constexpr int NT   = (PASSES == 3) ? 4 : (PASSES == 2) ? 3 : 2;
    constexpr int BIDX = (PASSES == 1) ? 1 : 2;
    __shared__ u16 lds[2][NT][128*64];

    const int t    = threadIdx.x;
    const int lane = t & 63, wave = t >> 6;
    const int l15  = lane & 15, l4 = lane >> 4;
    const int wr   = wave >> 1, wc = wave & 1;
    const int w64  = wave << 6;
    const int m0   = blockIdx.y * 128, n0 = blockIdx.x * 128;

    const u16* srcs[NT];
    srcs[0] = Ah + (size_t)m0*1024;
    if (PASSES >= 2) srcs[1] = Al + (size_t)m0*1024;
    srcs[BIDX] = Bh + (size_t)n0*1024;
    if (PASSES == 3) srcs[3] = Bl + (size_t)n0*1024;

    f32x4 acc[4][4];
    #pragma unroll
    for (int i = 0; i < 4; ++i)
        #pragma unroll
        for (int j = 0; j < 4; ++j) acc[i][j] = (f32x4){0.f,0.f,0.f,0.f};

#define STAGE(BUF, KOFF) do {                                                  \
    _Pragma("unroll")                                                          \
    for (int tl_ = 0; tl_ < NT; ++tl_) {                                       \
        _Pragma("unroll")                                                      \
        for (int it_ = 0; it_ < 4; ++it_) {                                    \
            const int idx_ = it_*256 + t;                                      \
            const int row_ = idx_ >> 3;                                        \
            const int c_   = (idx_ & 7) ^ (row_ & 7);                          \
            gload16(srcs[tl_] + (KOFF) + (size_t)row_*1024 + c_*8,             \
                    &lds[BUF][tl_][(it_*256 + w64)*8]);                        \
        }                                                                      \
    }                                                                          \
} while(0)

#define COMPUTE(BUF) do {                                                      \
    _Pragma("unroll")                                                          \
    for (int kk_ = 0; kk_ < 2; ++kk_) {                                        \
        const int cb_ = (kk_<<2) + l4;                                         \
        bf16x8 ah_[4], al_[4];                                                 \
        _Pragma("unroll")                                                      \
        for (int i_ = 0; i_ < 4; ++i_) {                                       \
            const int row_ = (wr<<6) + (i_<<4) + l15;                          \
            const int off_ = (row_<<6) + ((cb_ ^ (row_&7)) << 3);              \
            ah_[i_] = *(const bf16x8*)&lds[BUF][0][off_];                      \
            if (PASSES >= 2) al_[i_] = *(const bf16x8*)&lds[BUF][1][off_];     \
        }                                                                      \
        _Pragma("unroll")                                                      \
        for (int j_ = 0; j_ < 4; ++j_) {                                       \
            const int row_ = (wc<<6) + (j_<<4) + l15;                          \
            const int off_ = (row_<<6) + ((cb_ ^ (row_&7)) << 3);              \
            bf16x8 bh_ = *(const bf16x8*)&lds[BUF][BIDX][off_];                \
            bf16x8 bl_;                                                        \
            if (PASSES == 3) bl_ = *(const bf16x8*)&lds[BUF][3][off_];         \
            _Pragma("unroll")                                                  \
            for (int i_ = 0; i_ < 4; ++i_) {                                   \
                acc[i_][j_] = mfma16(ah_[i_], bh_, acc[i_][j_]);               \
                if (PASSES == 3) acc[i_][j_] = mfma16(ah_[i_], bl_, acc[i_][j_]); \
                if (PASSES >= 2) acc[i_][j_] = mfma16(al_[i_], bh_, acc[i_][j_]); \
            }                                                                  \
        }                                                                      \
    }                                                                          \
} while(0)

    STAGE(0, 0);
    __syncthreads();
    int cur = 0;
    for (int s = 0; s < 15; ++s) {
        if (cur == 0) STAGE(1, (s+1)*64);
        else          STAGE(0, (s+1)*64);
        COMPUTE(cur);
        __syncthreads();
        cur ^= 1;
    }
    COMPUTE(cur);
#undef STAGE
#undef COMPUTE

    // ---- epilogue ----
    #pragma unroll
    for (int i = 0; i < 4; ++i)
        #pragma unroll
        for (int j = 0; j < 4; ++j)
            #pragma unroll
            for (int r = 0; r < 4; ++r) {
                const int m = m0 + (wr<<6) + (i<<4) + (l4<<2) + r;
                const int n = n0 + (wc<<6) + (j<<4) + l15;
                const float v = acc[i][j][r];
                if (MODE == 0) {
                    outF[(size_t)m*N + n] = v + bias[n];
                } else if (MODE == 2) {
                    outH[(size_t)m*N + n] = f2bf(v + bias[n]);
                } else if (MODE == 3) {
                    outH[(size_t)m*N + n] = f2bf(v + bias[m]);
                } else {
                    const float pre = v + bias[n] + trust[m]*wlast[n];
                    const float g = 1.f/(1.f + __expf(-pre));
                    const float att = bf2f(attH[(size_t)m*N + n]) + bf2f(attL[(size_t)m*N + n]);
                    const float gated = att*g;
                    const unsigned short hb = f2bf(gated);
                    outH[(size_t)m*N + n] = hb;
                    outL[(size_t)m*N + n] = f2bf(gated - bf2f(hb));
                }
            }
}

// ---------------- Attention v5: K-half-split phases, 33 KB LDS, <=64 VGPR ----------------
// Block: 16 q rows x (b,h), 512 threads / 8 waves; wave w owns keys [w*128, w*128+128).
// Phase ph stores EVERY wave's sacc[4ph..4ph+4) (keys w*128+ph*64 .. +64) into the 32KB
// strip -> sacc half statically dead after its store (spill-free at 64 VGPR).
// Strip slot s = w*64 + j  <->  key = w*128 + ph*64 + j. Writes are 256B-contiguous runs.
__global__ __launch_bounds__(512, 8)
void attn_kernel(const u16* __restrict__ Qb, const u16* __restrict__ Kb,
                 const u16* __restrict__ Vt, const u16* __restrict__ T,
                 const int* __restrict__ mask,
                 float* __restrict__ attnOut, u16* __restrict__ attH, u16* __restrict__ attL)
{
    __shared__ float P[16*512];       // 32 KB strip (aliased for O reduce at the end)
    __shared__ float redA[8][16];
    __shared__ float redB[8][16];
    __shared__ int   mqv[16];

    const int t    = threadIdx.x;
    const int lane = t & 63, wave = t >> 6;     // 8 waves
    const int l15  = lane & 15, l4 = lane >> 4;
    const int q0   = blockIdx.x * 16, h = blockIdx.y, b = blockIdx.z;
    const int wk0  = wave * 128;

    if (t < 16) mqv[t] = mask[b*SS + q0 + t];

    const u16* Qp = Qb + ((size_t)(b*SS + q0 + l15))*DD + h*HDD + l4*8;
    bf16x8 qf0 = *(const bf16x8*)Qp;
    bf16x8 qf1 = *(const bf16x8*)(Qp + 32);

    const u16* Tbase = T + ((size_t)b*SS + q0 + l4*4)*SS + wk0 + l15;
    __syncthreads();

    // ---- QK^T: 8 key tiles of 16 per wave ----
    f32x4 sacc[8];
    #pragma unroll
    for (int tt = 0; tt < 8; ++tt) sacc[tt] = (f32x4){0.f,0.f,0.f,0.f};

    const u16* Kbase = Kb + ((size_t)(b*SS + wk0 + l15))*DD + h*HDD + l4*8;
    #pragma unroll
    for (int tt = 0; tt < 8; ++tt) {
        const u16* Kp = Kbase + (size_t)tt*(16*DD);
        bf16x8 kf0 = *(const bf16x8*)Kp;
        bf16x8 kf1 = *(const bf16x8*)(Kp + 32);
        sacc[tt] = mfma16(qf0, kf0, sacc[tt]);
        sacc[tt] = mfma16(qf1, kf1, sacc[tt]);
    }

    // ---- bias + mask + wave-local row-max ----
    int mrow[4];
    #pragma unroll
    for (int r = 0; r < 4; ++r) mrow[r] = mqv[l4*4 + r];

    float mx[4] = {-3e38f, -3e38f, -3e38f, -3e38f};
    #pragma unroll
    for (int tt = 0; tt < 8; ++tt) {
        #pragma unroll
        for (int r = 0; r < 4; ++r) {
            const float bias = bf2f(Tbase[(size_t)r*SS + tt*16]);
            float s = sacc[tt][r]*0.125f + bias;
            s = mrow[r] ? s : -1e9f;
            sacc[tt][r] = s;
            mx[r] = fmaxf(mx[r], s);
        }
    }
    #pragma unroll
    for (int r = 0; r < 4; ++r)
        #pragma unroll
        for (int xm = 1; xm < 16; xm <<= 1) mx[r] = fmaxf(mx[r], __shfl_xor(mx[r], xm));
    if (l15 == 0) {
        #pragma unroll
        for (int r = 0; r < 4; ++r) redA[wave][l4*4 + r] = mx[r];
    }
    __syncthreads();

    float mxa[4];
    #pragma unroll
    for (int r = 0; r < 4; ++r) {
        const int row = l4*4 + r;
        float m = redA[0][row];
        #pragma unroll
        for (int w = 1; w < 8; ++w) m = fmaxf(m, redA[w][row]);
        mxa[r] = m;
    }

    // ---- exp in regs + row-sum ----
    float sum[4] = {0.f, 0.f, 0.f, 0.f};
    #pragma unroll
    for (int tt = 0; tt < 8; ++tt)
        #pragma unroll
        for (int r = 0; r < 4; ++r) {
            const float p = __expf(sacc[tt][r] - mxa[r]);
            sacc[tt][r] = p;
            sum[r] += p;
        }
    #pragma unroll
    for (int r = 0; r < 4; ++r)
        #pragma unroll
        for (int xm = 1; xm < 16; xm <<= 1) sum[r] += __shfl_xor(sum[r], xm);
    if (l15 == 0) {
        #pragma unroll
        for (int r = 0; r < 4; ++r) redB[wave][l4*4 + r] = sum[r];
    }
    __syncthreads();

    // row inverse sums
    float inv4[4];
    #pragma unroll
    for (int r = 0; r < 4; ++r) {
        const int row = l4*4 + r;
        float s8 = 0.f;
        #pragma unroll
        for (int w = 0; w < 8; ++w) s8 += redB[w][row];
        inv4[r] = 1.f / s8;
    }
    const int wrow = t >> 5;              // attn-write row (16 rows, 32 threads each)
    const int wcl  = t & 31;
    float wiv;
    {
        float s8 = 0.f;
        #pragma unroll
        for (int w = 0; w < 8; ++w) s8 += redB[w][wrow];
        wiv = 1.f / s8;
    }
    float* gRow = attnOut + ((size_t)(b*HH + h))*SS*SS + (size_t)(q0 + wrow)*SS;

    const u16* Vw = Vt + ((size_t)(h*HDD + l15))*MTOT + b*SS + wk0;
    f32x4 pv[4];
    #pragma unroll
    for (int nt = 0; nt < 4; ++nt) pv[nt] = (f32x4){0.f,0.f,0.f,0.f};

    // ================= two K-half phases (all waves active in both) =================
    #pragma unroll
    for (int ph = 0; ph < 2; ++ph) {
        // store sacc[4ph .. 4ph+4): wave's keys w*128 + ph*64 + [0,64) -> slots w*64 + j
        #pragma unroll
        for (int t2 = 0; t2 < 4; ++t2) {
            const int slot = wave*64 + t2*16 + l15;
            const int c = slot >> 2, jj = slot & 3;
            #pragma unroll
            for (int r = 0; r < 4; ++r) {
                const int row = l4*4 + r;
                P[row*512 + ((c ^ (row & 7)) << 2) + jj] = sacc[4*ph + t2][r];
            }
        }
        __syncthreads();

        // stream this phase's attn columns (normalized), 256B-contiguous runs
        #pragma unroll
        for (int i = 0; i < 4; ++i) {
            const int c  = wcl + i*32;          // chunk 0..127
            const int sb = c*4;                 // slot base
            f32x4 v = *(f32x4*)&P[wrow*512 + ((c ^ (wrow & 7)) << 2)];
            v *= wiv;
            const int kg = (sb >> 6)*128 + ph*64 + (sb & 63);
            *(f32x4*)&gRow[kg] = v;
        }

        // PV over this phase's 64-key segment (2 k-groups of 32)
        #pragma unroll
        for (int t2 = 0; t2 < 2; ++t2) {
            const int c0 = wave*16 + t2*8 + l4*2;
            f32x4 a0 = *(f32x4*)&P[l15*512 + (((c0    ) ^ (l15 & 7)) << 2)];
            f32x4 a1 = *(f32x4*)&P[l15*512 + (((c0 + 1) ^ (l15 & 7)) << 2)];
            bf16x8 af;
            af[0] = (__bf16)a0[0]; af[1] = (__bf16)a0[1]; af[2] = (__bf16)a0[2]; af[3] = (__bf16)a0[3];
            af[4] = (__bf16)a1[0]; af[5] = (__bf16)a1[1]; af[6] = (__bf16)a1[2]; af[7] = (__bf16)a1[3];
            const u16* Vp = Vw + ph*64 + t2*32 + l4*8;
            #pragma unroll
            for (int nt = 0; nt < 4; ++nt) {
                bf16x8 bf = *(const bf16x8*)(Vp + (size_t)nt*16*MTOT);
                pv[nt] = mfma16(af, bf, pv[nt]);
            }
        }
        __syncthreads();   // strip consumed before overwrite / final alias
    }

    // ---- cross-wave reduce through LDS (alias P = 8192 floats), scaled by 1/sum ----
    float* pw = P + wave*1024;
    #pragma unroll
    for (int nt = 0; nt < 4; ++nt)
        #pragma unroll
        for (int r = 0; r < 4; ++r)
            pw[(l4*4 + r)*64 + nt*16 + l15] = pv[nt][r] * inv4[r];
    __syncthreads();

    {
        const int q = t >> 5, d0 = (t & 31)*2;
        float sx = 0.f, sy = 0.f;
        #pragma unroll
        for (int w = 0; w < 8; ++w) {
            float2 v = *(float2*)&P[w*1024 + q*64 + d0];
            sx += v.x; sy += v.y;
        }
        const size_t off = ((size_t)(b*SS + q0 + q))*DD + h*HDD + d0;
        const unsigned short h0 = f2bf(sx), h1 = f2bf(sy);
        ushort2 hh = {h0, h1};
        ushort2 ll = {f2bf(sx - bf2f(h0)), f2bf(sy - bf2f(h1))};
        *(ushort2*)&attH[off] = hh;
        *(ushort2*)&attL[off] = ll;
    }
}

extern "C" void kernel_launch(void* const* d_in, const int* in_sizes, int n_in,
                              void* d_out, int out_size, void* d_ws, size_t ws_size,
                              hipStream_t stream) {
    const float* x     = (const float*)d_in[0];
    const float* trust = (const float*)d_in[1];
    const int*   mask  = (const int*)  d_in[2];
    const float* Wq    = (const float*)d_in[3];
    const float* bq    = (const float*)d_in[4];
    const float* Wk    = (const float*)d_in[5];
    const float* bk    = (const float*)d_in[6];
    const float* Wv    = (const float*)d_in[7];
    const float* bv    = (const float*)d_in[8];
    const float* Wtp   = (const float*)d_in[9];
    const float* btp   = (const float*)d_in[10];
    const float* Wg    = (const float*)d_in[11];
    const float* bg    = (const float*)d_in[12];
    const float* Wo    = (const float*)d_in[13];
    const float* bo    = (const float*)d_in[14];

    float* out     = (float*)d_out;
    float* attnOut = out + (size_t)MTOT * DD;

    char* ws = (char*)d_ws;
    u16* xh   = (u16*)(ws + (size_t)0*MB);    // 8 MB -> attH later
    u16* xl   = (u16*)(ws + (size_t)8*MB);    // 8 MB -> attL later
    u16* WqTh = (u16*)(ws + (size_t)16*MB);
    u16* WkTh = (u16*)(ws + (size_t)18*MB);
    u16* WvTh = (u16*)(ws + (size_t)20*MB);
    u16* WgTh = (u16*)(ws + (size_t)22*MB);
    u16* WoTh = (u16*)(ws + (size_t)24*MB);
    u16* WoTl = (u16*)(ws + (size_t)26*MB);
    u16* Qbf  = (u16*)(ws + (size_t)28*MB);   // 8 MB -> Gh later
    u16* Kbf  = (u16*)(ws + (size_t)36*MB);   // 8 MB -> Gl later
    u16* Vt   = (u16*)(ws + (size_t)44*MB);   // 8 MB
    u16* Tb   = (u16*)(ws + (size_t)52*MB);   // 8 MB bf16 trust-bias table
    float* tconst = (float*)(ws + (size_t)60*MB);
    u16* attH = xh;
    u16* attL = xl;
    u16* Gh   = Qbf;
    u16* Gl   = Kbf;

    const dim3 blk(256);

    tconst_kernel<<<1, 64, 0, stream>>>(Wtp, btp, tconst);
    tbias_kernel<<<dim3(SS, BB), blk, 0, stream>>>(trust, tconst, Tb);
    split_kernel<<<2048, blk, 0, stream>>>(x, xh, xl, MTOT*DD/4);
    tsplit5_kernel<<<dim3(16, 16, 5), blk, 0, stream>>>(
        Wq, WqTh, Wk, WkTh, Wv, WvTh, Wg, WgTh, Wo, WoTh, WoTl);

    // Q, K: 2-pass (AhBh + AlBh), bf16 out
    mgemm<2,2><<<dim3(DD/128, MTOT/128), blk, 0, stream>>>(
        xh, xl, WqTh, nullptr, bq, nullptr, Qbf, nullptr, MTOT, DD,
        nullptr, nullptr, nullptr, nullptr);
    mgemm<2,2><<<dim3(DD/128, MTOT/128), blk, 0, stream>>>(
        xh, xl, WkTh, nullptr, bk, nullptr, Kbf, nullptr, MTOT, DD,
        nullptr, nullptr, nullptr, nullptr);
    // V^T: 1-pass, C[d_glob][m] = WvT @ x^T (bias by row)
    mgemm<3,1><<<dim3(MTOT/128, DD/128), blk, 0, stream>>>(
        WvTh, nullptr, xh, nullptr, bv, nullptr, Vt, nullptr, DD, MTOT,
        nullptr, nullptr, nullptr, nullptr);

    attn_kernel<<<dim3(SS/16, HH, BB), dim3(512), 0, stream>>>(
        Qbf, Kbf, Vt, Tb, mask, attnOut, attH, attL);

    // gate: 1-pass; gated = attended * sigmoid(attended@Wg[0:1024] + bg + trust*wlast)
    mgemm<1,1><<<dim3(DD/128, MTOT/128), blk, 0, stream>>>(
        attH, nullptr, WgTh, nullptr, bg, nullptr, Gh, Gl, MTOT, DD,
        trust, Wg + (size_t)DD*DD, attH, attL);
    // out = gated @ Wo + bo (fp32, 3-pass)
    mgemm<0,3><<<dim3(DD/128, MTOT/128), blk, 0, stream>>>(
        Gh, Gl, WoTh, WoTl, bo, out, nullptr, nullptr, MTOT, DD,
        nullptr, nullptr, nullptr, nullptr);
}

// Round 9
// 303.031 us; speedup vs baseline: 1.4370x; 1.1210x over previous
//
#include <hip/hip_runtime.h>
#include <math.h>

#define BB 4
#define SS 1024
#define DD 1024
#define HH 16
#define HDD 64
#define MTOT (BB*SS)   // 4096
#define MB (1024*1024)

typedef float  f32x4  __attribute__((ext_vector_type(4)));
typedef __bf16 bf16x8 __attribute__((ext_vector_type(8)));
typedef unsigned short u16;

__device__ __forceinline__ unsigned short f2bf(float f) {
    union { float f; unsigned u; } v; v.f = f;
    unsigned r = v.u + 0x7FFFu + ((v.u >> 16) & 1u);
    return (unsigned short)(r >> 16);
}
__device__ __forceinline__ float bf2f(unsigned short u) {
    union { unsigned u; float f; } v; v.u = ((unsigned)u) << 16;
    return v.f;
}
__device__ __forceinline__ f32x4 mfma16(bf16x8 a, bf16x8 b, f32x4 c) {
    return __builtin_amdgcn_mfma_f32_16x16x32_bf16(a, b, c, 0, 0, 0);
}
__device__ __forceinline__ void gload16(const void* g, void* l) {
    __builtin_amdgcn_global_load_lds(
        (const __attribute__((address_space(1))) void*)g,
        (__attribute__((address_space(3))) void*)l, 16, 0, 0);
}

// ---------------- split: fp32 -> bf16 hi/lo ----------------
__global__ void split_kernel(const float* __restrict__ in, u16* __restrict__ hi,
                             u16* __restrict__ lo, int n4)
{
    for (int i = blockIdx.x*blockDim.x + threadIdx.x; i < n4; i += gridDim.x*blockDim.x) {
        f32x4 v = ((const f32x4*)in)[i];
        ushort4 h4, l4;
        h4.x = f2bf(v[0]); l4.x = f2bf(v[0] - bf2f(h4.x));
        h4.y = f2bf(v[1]); l4.y = f2bf(v[1] - bf2f(h4.y));
        h4.z = f2bf(v[2]); l4.z = f2bf(v[2] - bf2f(h4.z));
        h4.w = f2bf(v[3]); l4.w = f2bf(v[3] - bf2f(h4.w));
        ((ushort4*)hi)[i] = h4; ((ushort4*)lo)[i] = l4;
    }
}

// ------- fused transpose+split for all 5 weights: W[k][n] -> WT hi (+opt lo) [n][k] -------
__global__ __launch_bounds__(256)
void tsplit5_kernel(const float* W0, u16* h0,
                    const float* W1, u16* h1,
                    const float* W2, u16* h2,
                    const float* W3, u16* h3,
                    const float* W4, u16* h4, u16* l4T)
{
    const float* W; u16* hT; u16* lT = nullptr;
    switch (blockIdx.z) {
        case 0: W = W0; hT = h0; break;
        case 1: W = W1; hT = h1; break;
        case 2: W = W2; hT = h2; break;
        case 3: W = W3; hT = h3; break;
        default: W = W4; hT = h4; lT = l4T; break;
    }
    __shared__ float tile[64][65];
    const int t  = threadIdx.x;
    const int k0 = blockIdx.y * 64, n0 = blockIdx.x * 64;
    const int r  = t >> 4, c4 = (t & 15) * 4;
    #pragma unroll
    for (int rr = 0; rr < 4; ++rr) {
        const int k = r + rr*16;
        f32x4 v = *(const f32x4*)&W[(size_t)(k0 + k)*1024 + n0 + c4];
        tile[k][c4+0] = v[0]; tile[k][c4+1] = v[1]; tile[k][c4+2] = v[2]; tile[k][c4+3] = v[3];
    }
    __syncthreads();
    #pragma unroll
    for (int rr = 0; rr < 4; ++rr) {
        const int nl = r + rr*16;
        ushort4 hh, ll;
        {
            float v;
            v = tile[c4+0][nl]; hh.x = f2bf(v); ll.x = f2bf(v - bf2f(hh.x));
            v = tile[c4+1][nl]; hh.y = f2bf(v); ll.y = f2bf(v - bf2f(hh.y));
            v = tile[c4+2][nl]; hh.z = f2bf(v); ll.z = f2bf(v - bf2f(hh.z));
            v = tile[c4+3][nl]; hh.w = f2bf(v); ll.w = f2bf(v - bf2f(hh.w));
        }
        *(ushort4*)&hT[(size_t)(n0 + nl)*1024 + k0 + c4] = hh;
        if (lT) *(ushort4*)&lT[(size_t)(n0 + nl)*1024 + k0 + c4] = ll;
    }
}

// ---------------- trust-affinity rank-1 constants ----------------
__global__ void tconst_kernel(const float* __restrict__ Wtp, const float* __restrict__ btp,
                              float* __restrict__ out3)
{
    const int l = threadIdx.x;   // 64 threads
    const float w = Wtp[l], b = btp[l];
    float a = w*w, m = w*b, c = b*b;
    #pragma unroll
    for (int s = 32; s; s >>= 1) {
        a += __shfl_down(a, s);
        m += __shfl_down(m, s);
        c += __shfl_down(c, s);
    }
    if (l == 0) { out3[0] = a; out3[1] = m; out3[2] = c; }
}

// ---------------- trust bias table: T[b][q][k] = bf16(0.1*sigmoid(ta)) ----------------
__global__ __launch_bounds__(256)
void tbias_kernel(const float* __restrict__ trust, const float* __restrict__ tconst,
                  u16* __restrict__ T)
{
    const int b = blockIdx.y;
    const int q = blockIdx.x;
    const float tq = trust[b*SS + q];
    const float c1 = tconst[0], c2 = tconst[1], c3 = tconst[2];
    const int k0 = threadIdx.x * 4;
    f32x4 tk = *(const f32x4*)&trust[b*SS + k0];
    ushort4 o;
    #pragma unroll
    for (int j = 0; j < 4; ++j) {
        const float ta = c1*tq*tk[j] + c2*(tq + tk[j]) + c3;
        const float v  = 0.1f/(1.f + __expf(-ta));
        ((u16*)&o)[j] = f2bf(v);
    }
    *(ushort4*)&T[((size_t)b*SS + q)*SS + k0] = o;
}

// ---------------- split-bf16 MFMA GEMM ----------------
// PASSES=3: AhBh + AhBl + AlBh ; PASSES=2: AhBh + AlBh ; PASSES=1: AhBh
template<int MODE, int PASSES>
__global__ __launch_bounds__(256)
void mgemm(const u16* __restrict__ Ah, const u16* __restrict__ Al,
           const u16* __restrict__ Bh, const u16* __restrict__ Bl,
           const float* __restrict__ bias,
           float* __restrict__ outF, u16* __restrict__ outH, u16* __restrict__ outL,
           int M, int N,
           const float* __restrict__ trust, const float* __restrict__ wlast,
           const u16* __restrict__ attH, const u16* __restrict__ attL)
{
    constexpr int NT   = (PASSES == 3) ? 4 : (PASSES == 2) ? 3 : 2;
    constexpr int BIDX = (PASSES == 1) ? 1 : 2;
    __shared__ u16 lds[2][NT][128*64];

    const int t    = threadIdx.x;
    const int lane = t & 63, wave = t >> 6;
    const int l15  = lane & 15, l4 = lane >> 4;
    const int wr   = wave >> 1, wc = wave & 1;
    const int w64  = wave << 6;
    const int m0   = blockIdx.y * 128, n0 = blockIdx.x * 128;

    const u16* srcs[NT];
    srcs[0] = Ah + (size_t)m0*1024;
    if (PASSES >= 2) srcs[1] = Al + (size_t)m0*1024;
    srcs[BIDX] = Bh + (size_t)n0*1024;
    if (PASSES == 3) srcs[3] = Bl + (size_t)n0*1024;

    f32x4 acc[4][4];
    #pragma unroll
    for (int i = 0; i < 4; ++i)
        #pragma unroll
        for (int j = 0; j < 4; ++j) acc[i][j] = (f32x4){0.f,0.f,0.f,0.f};

#define STAGE(BUF, KOFF) do {                                                  \
    _Pragma("unroll")                                                          \
    for (int tl_ = 0; tl_ < NT; ++tl_) {                                       \
        _Pragma("unroll")                                                      \
        for (int it_ = 0; it_ < 4; ++it_) {                                    \
            const int idx_ = it_*256 + t;                                      \
            const int row_ = idx_ >> 3;                                        \
            const int c_   = (idx_ & 7) ^ (row_ & 7);                          \
            gload16(srcs[tl_] + (KOFF) + (size_t)row_*1024 + c_*8,             \
                    &lds[BUF][tl_][(it_*256 + w64)*8]);                        \
        }                                                                      \
    }                                                                          \
} while(0)

#define COMPUTE(BUF) do {                                                      \
    _Pragma("unroll")                                                          \
    for (int kk_ = 0; kk_ < 2; ++kk_) {                                        \
        const int cb_ = (kk_<<2) + l4;                                         \
        bf16x8 ah_[4], al_[4];                                                 \
        _Pragma("unroll")                                                      \
        for (int i_ = 0; i_ < 4; ++i_) {                                       \
            const int row_ = (wr<<6) + (i_<<4) + l15;                          \
            const int off_ = (row_<<6) + ((cb_ ^ (row_&7)) << 3);              \
            ah_[i_] = *(const bf16x8*)&lds[BUF][0][off_];                      \
            if (PASSES >= 2) al_[i_] = *(const bf16x8*)&lds[BUF][1][off_];     \
        }                                                                      \
        _Pragma("unroll")                                                      \
        for (int j_ = 0; j_ < 4; ++j_) {                                       \
            const int row_ = (wc<<6) + (j_<<4) + l15;                          \
            const int off_ = (row_<<6) + ((cb_ ^ (row_&7)) << 3);              \
            bf16x8 bh_ = *(const bf16x8*)&lds[BUF][BIDX][off_];                \
            bf16x8 bl_;                                                        \
            if (PASSES == 3) bl_ = *(const bf16x8*)&lds[BUF][3][off_];         \
            _Pragma("unroll")                                                  \
            for (int i_ = 0; i_ < 4; ++i_) {                                   \
                acc[i_][j_] = mfma16(ah_[i_], bh_, acc[i_][j_]);               \
                if (PASSES == 3) acc[i_][j_] = mfma16(ah_[i_], bl_, acc[i_][j_]); \
                if (PASSES >= 2) acc[i_][j_] = mfma16(al_[i_], bh_, acc[i_][j_]); \
            }                                                                  \
        }                                                                      \
    }                                                                          \
} while(0)

    STAGE(0, 0);
    __syncthreads();
    int cur = 0;
    for (int s = 0; s < 15; ++s) {
        if (cur == 0) STAGE(1, (s+1)*64);
        else          STAGE(0, (s+1)*64);
        COMPUTE(cur);
        __syncthreads();
        cur ^= 1;
    }
    COMPUTE(cur);
#undef STAGE
#undef COMPUTE

    // ---- epilogue ----
    #pragma unroll
    for (int i = 0; i < 4; ++i)
        #pragma unroll
        for (int j = 0; j < 4; ++j)
            #pragma unroll
            for (int r = 0; r < 4; ++r) {
                const int m = m0 + (wr<<6) + (i<<4) + (l4<<2) + r;
                const int n = n0 + (wc<<6) + (j<<4) + l15;
                const float v = acc[i][j][r];
                if (MODE == 0) {
                    outF[(size_t)m*N + n] = v + bias[n];
                } else if (MODE == 2) {
                    outH[(size_t)m*N + n] = f2bf(v + bias[n]);
                } else if (MODE == 3) {
                    outH[(size_t)m*N + n] = f2bf(v + bias[m]);
                } else {
                    const float pre = v + bias[n] + trust[m]*wlast[n];
                    const float g = 1.f/(1.f + __expf(-pre));
                    const float att = bf2f(attH[(size_t)m*N + n]) + bf2f(attL[(size_t)m*N + n]);
                    const float gated = att*g;
                    const unsigned short hb = f2bf(gated);
                    outH[(size_t)m*N + n] = hb;
                    outL[(size_t)m*N + n] = f2bf(gated - bf2f(hb));
                }
            }
}

// ---------------- Attention v6: K-half-split phases, 33 KB LDS, (512,4) bounds ----------------
// Identical structure to v5; __launch_bounds__(512,4) -> 64-VGPR cap (round-6-proven clean
// allocation), LDS 33 KB -> 4 blocks/CU from both LDS and VGPR budgets.
__global__ __launch_bounds__(512, 4)
void attn_kernel(const u16* __restrict__ Qb, const u16* __restrict__ Kb,
                 const u16* __restrict__ Vt, const u16* __restrict__ T,
                 const int* __restrict__ mask,
                 float* __restrict__ attnOut, u16* __restrict__ attH, u16* __restrict__ attL)
{
    __shared__ float P[16*512];       // 32 KB strip (aliased for O reduce at the end)
    __shared__ float redA[8][16];
    __shared__ float redB[8][16];
    __shared__ int   mqv[16];

    const int t    = threadIdx.x;
    const int lane = t & 63, wave = t >> 6;     // 8 waves
    const int l15  = lane & 15, l4 = lane >> 4;
    const int q0   = blockIdx.x * 16, h = blockIdx.y, b = blockIdx.z;
    const int wk0  = wave * 128;

    if (t < 16) mqv[t] = mask[b*SS + q0 + t];

    const u16* Qp = Qb + ((size_t)(b*SS + q0 + l15))*DD + h*HDD + l4*8;
    bf16x8 qf0 = *(const bf16x8*)Qp;
    bf16x8 qf1 = *(const bf16x8*)(Qp + 32);

    const u16* Tbase = T + ((size_t)b*SS + q0 + l4*4)*SS + wk0 + l15;
    __syncthreads();

    // ---- QK^T: 8 key tiles of 16 per wave ----
    f32x4 sacc[8];
    #pragma unroll
    for (int tt = 0; tt < 8; ++tt) sacc[tt] = (f32x4){0.f,0.f,0.f,0.f};

    const u16* Kbase = Kb + ((size_t)(b*SS + wk0 + l15))*DD + h*HDD + l4*8;
    #pragma unroll
    for (int tt = 0; tt < 8; ++tt) {
        const u16* Kp = Kbase + (size_t)tt*(16*DD);
        bf16x8 kf0 = *(const bf16x8*)Kp;
        bf16x8 kf1 = *(const bf16x8*)(Kp + 32);
        sacc[tt] = mfma16(qf0, kf0, sacc[tt]);
        sacc[tt] = mfma16(qf1, kf1, sacc[tt]);
    }

    // ---- bias + mask + wave-local row-max ----
    int mrow[4];
    #pragma unroll
    for (int r = 0; r < 4; ++r) mrow[r] = mqv[l4*4 + r];

    float mx[4] = {-3e38f, -3e38f, -3e38f, -3e38f};
    #pragma unroll
    for (int tt = 0; tt < 8; ++tt) {
        #pragma unroll
        for (int r = 0; r < 4; ++r) {
            const float bias = bf2f(Tbase[(size_t)r*SS + tt*16]);
            float s = sacc[tt][r]*0.125f + bias;
            s = mrow[r] ? s : -1e9f;
            sacc[tt][r] = s;
            mx[r] = fmaxf(mx[r], s);
        }
    }
    #pragma unroll
    for (int r = 0; r < 4; ++r)
        #pragma unroll
        for (int xm = 1; xm < 16; xm <<= 1) mx[r] = fmaxf(mx[r], __shfl_xor(mx[r], xm));
    if (l15 == 0) {
        #pragma unroll
        for (int r = 0; r < 4; ++r) redA[wave][l4*4 + r] = mx[r];
    }
    __syncthreads();

    float mxa[4];
    #pragma unroll
    for (int r = 0; r < 4; ++r) {
        const int row = l4*4 + r;
        float m = redA[0][row];
        #pragma unroll
        for (int w = 1; w < 8; ++w) m = fmaxf(m, redA[w][row]);
        mxa[r] = m;
    }

    // ---- exp in regs + row-sum ----
    float sum[4] = {0.f, 0.f, 0.f, 0.f};
    #pragma unroll
    for (int tt = 0; tt < 8; ++tt)
        #pragma unroll
        for (int r = 0; r < 4; ++r) {
            const float p = __expf(sacc[tt][r] - mxa[r]);
            sacc[tt][r] = p;
            sum[r] += p;
        }
    #pragma unroll
    for (int r = 0; r < 4; ++r)
        #pragma unroll
        for (int xm = 1; xm < 16; xm <<= 1) sum[r] += __shfl_xor(sum[r], xm);
    if (l15 == 0) {
        #pragma unroll
        for (int r = 0; r < 4; ++r) redB[wave][l4*4 + r] = sum[r];
    }
    __syncthreads();

    // row inverse sums
    float inv4[4];
    #pragma unroll
    for (int r = 0; r < 4; ++r) {
        const int row = l4*4 + r;
        float s8 = 0.f;
        #pragma unroll
        for (int w = 0; w < 8; ++w) s8 += redB[w][row];
        inv4[r] = 1.f / s8;
    }
    const int wrow = t >> 5;              // attn-write row (16 rows, 32 threads each)
    const int wcl  = t & 31;
    float wiv;
    {
        float s8 = 0.f;
        #pragma unroll
        for (int w = 0; w < 8; ++w) s8 += redB[w][wrow];
        wiv = 1.f / s8;
    }
    float* gRow = attnOut + ((size_t)(b*HH + h))*SS*SS + (size_t)(q0 + wrow)*SS;

    const u16* Vw = Vt + ((size_t)(h*HDD + l15))*MTOT + b*SS + wk0;
    f32x4 pv[4];
    #pragma unroll
    for (int nt = 0; nt < 4; ++nt) pv[nt] = (f32x4){0.f,0.f,0.f,0.f};

    // ================= two K-half phases (all waves active in both) =================
    #pragma unroll
    for (int ph = 0; ph < 2; ++ph) {
        // store sacc[4ph .. 4ph+4): wave's keys w*128 + ph*64 + [0,64) -> slots w*64 + j
        #pragma unroll
        for (int t2 = 0; t2 < 4; ++t2) {
            const int slot = wave*64 + t2*16 + l15;
            const int c = slot >> 2, jj = slot & 3;
            #pragma unroll
            for (int r = 0; r < 4; ++r) {
                const int row = l4*4 + r;
                P[row*512 + ((c ^ (row & 7)) << 2) + jj] = sacc[4*ph + t2][r];
            }
        }
        __syncthreads();

        // stream this phase's attn columns (normalized), 256B-contiguous runs
        #pragma unroll
        for (int i = 0; i < 4; ++i) {
            const int c  = wcl + i*32;          // chunk 0..127
            const int sb = c*4;                 // slot base
            f32x4 v = *(f32x4*)&P[wrow*512 + ((c ^ (wrow & 7)) << 2)];
            v *= wiv;
            const int kg = (sb >> 6)*128 + ph*64 + (sb & 63);
            *(f32x4*)&gRow[kg] = v;
        }

        // PV over this phase's 64-key segment (2 k-groups of 32)
        #pragma unroll
        for (int t2 = 0; t2 < 2; ++t2) {
            const int c0 = wave*16 + t2*8 + l4*2;
            f32x4 a0 = *(f32x4*)&P[l15*512 + (((c0    ) ^ (l15 & 7)) << 2)];
            f32x4 a1 = *(f32x4*)&P[l15*512 + (((c0 + 1) ^ (l15 & 7)) << 2)];
            bf16x8 af;
            af[0] = (__bf16)a0[0]; af[1] = (__bf16)a0[1]; af[2] = (__bf16)a0[2]; af[3] = (__bf16)a0[3];
            af[4] = (__bf16)a1[0]; af[5] = (__bf16)a1[1]; af[6] = (__bf16)a1[2]; af[7] = (__bf16)a1[3];
            const u16* Vp = Vw + ph*64 + t2*32 + l4*8;
            #pragma unroll
            for (int nt = 0; nt < 4; ++nt) {
                bf16x8 bf = *(const bf16x8*)(Vp + (size_t)nt*16*MTOT);
                pv[nt] = mfma16(af, bf, pv[nt]);
            }
        }
        __syncthreads();   // strip consumed before overwrite / final alias
    }

    // ---- cross-wave reduce through LDS (alias P = 8192 floats), scaled by 1/sum ----
    float* pw = P + wave*1024;
    #pragma unroll
    for (int nt = 0; nt < 4; ++nt)
        #pragma unroll
        for (int r = 0; r < 4; ++r)
            pw[(l4*4 + r)*64 + nt*16 + l15] = pv[nt][r] * inv4[r];
    __syncthreads();

    {
        const int q = t >> 5, d0 = (t & 31)*2;
        float sx = 0.f, sy = 0.f;
        #pragma unroll
        for (int w = 0; w < 8; ++w) {
            float2 v = *(float2*)&P[w*1024 + q*64 + d0];
            sx += v.x; sy += v.y;
        }
        const size_t off = ((size_t)(b*SS + q0 + q))*DD + h*HDD + d0;
        const unsigned short h0 = f2bf(sx), h1 = f2bf(sy);
        ushort2 hh = {h0, h1};
        ushort2 ll = {f2bf(sx - bf2f(h0)), f2bf(sy - bf2f(h1))};
        *(ushort2*)&attH[off] = hh;
        *(ushort2*)&attL[off] = ll;
    }
}

extern "C" void kernel_launch(void* const* d_in, const int* in_sizes, int n_in,
                              void* d_out, int out_size, void* d_ws, size_t ws_size,
                              hipStream_t stream) {
    const float* x     = (const float*)d_in[0];
    const float* trust = (const float*)d_in[1];
    const int*   mask  = (const int*)  d_in[2];
    const float* Wq    = (const float*)d_in[3];
    const float* bq    = (const float*)d_in[4];
    const float* Wk    = (const float*)d_in[5];
    const float* bk    = (const float*)d_in[6];
    const float* Wv    = (const float*)d_in[7];
    const float* bv    = (const float*)d_in[8];
    const float* Wtp   = (const float*)d_in[9];
    const float* btp   = (const float*)d_in[10];
    const float* Wg    = (const float*)d_in[11];
    const float* bg    = (const float*)d_in[12];
    const float* Wo    = (const float*)d_in[13];
    const float* bo    = (const float*)d_in[14];

    float* out     = (float*)d_out;
    float* attnOut = out + (size_t)MTOT * DD;

    char* ws = (char*)d_ws;
    u16* xh   = (u16*)(ws + (size_t)0*MB);    // 8 MB -> attH later
    u16* xl   = (u16*)(ws + (size_t)8*MB);    // 8 MB -> attL later
    u16* WqTh = (u16*)(ws + (size_t)16*MB);
    u16* WkTh = (u16*)(ws + (size_t)18*MB);
    u16* WvTh = (u16*)(ws + (size_t)20*MB);
    u16* WgTh = (u16*)(ws + (size_t)22*MB);
    u16* WoTh = (u16*)(ws + (size_t)24*MB);
    u16* WoTl = (u16*)(ws + (size_t)26*MB);
    u16* Qbf  = (u16*)(ws + (size_t)28*MB);   // 8 MB -> Gh later
    u16* Kbf  = (u16*)(ws + (size_t)36*MB);   // 8 MB -> Gl later
    u16* Vt   = (u16*)(ws + (size_t)44*MB);   // 8 MB
    u16* Tb   = (u16*)(ws + (size_t)52*MB);   // 8 MB bf16 trust-bias table
    float* tconst = (float*)(ws + (size_t)60*MB);
    u16* attH = xh;
    u16* attL = xl;
    u16* Gh   = Qbf;
    u16* Gl   = Kbf;

    const dim3 blk(256);

    tconst_kernel<<<1, 64, 0, stream>>>(Wtp, btp, tconst);
    tbias_kernel<<<dim3(SS, BB), blk, 0, stream>>>(trust, tconst, Tb);
    split_kernel<<<2048, blk, 0, stream>>>(x, xh, xl, MTOT*DD/4);
    tsplit5_kernel<<<dim3(16, 16, 5), blk, 0, stream>>>(
        Wq, WqTh, Wk, WkTh, Wv, WvTh, Wg, WgTh, Wo, WoTh, WoTl);

    // Q, K: 2-pass (AhBh + AlBh), bf16 out
    mgemm<2,2><<<dim3(DD/128, MTOT/128), blk, 0, stream>>>(
        xh, xl, WqTh, nullptr, bq, nullptr, Qbf, nullptr, MTOT, DD,
        nullptr, nullptr, nullptr, nullptr);
    mgemm<2,2><<<dim3(DD/128, MTOT/128), blk, 0, stream>>>(
        xh, xl, WkTh, nullptr, bk, nullptr, Kbf, nullptr, MTOT, DD,
        nullptr, nullptr, nullptr, nullptr);
    // V^T: 1-pass, C[d_glob][m] = WvT @ x^T (bias by row)
    mgemm<3,1><<<dim3(MTOT/128, DD/128), blk, 0, stream>>>(
        WvTh, nullptr, xh, nullptr, bv, nullptr, Vt, nullptr, DD, MTOT,
        nullptr, nullptr, nullptr, nullptr);

    attn_kernel<<<dim3(SS/16, HH, BB), dim3(512), 0, stream>>>(
        Qbf, Kbf, Vt, Tb, mask, attnOut, attH, attL);

    // gate: 1-pass; gated = attended * sigmoid(attended@Wg[0:1024] + bg + trust*wlast)
    mgemm<1,1><<<dim3(DD/128, MTOT/128), blk, 0, stream>>>(
        attH, nullptr, WgTh, nullptr, bg, nullptr, Gh, Gl, MTOT, DD,
        trust, Wg + (size_t)DD*DD, attH, attL);
    // out = gated @ Wo + bo (fp32, 3-pass)
    mgemm<0,3><<<dim3(DD/128, MTOT/128), blk, 0, stream>>>(
        Gh, Gl, WoTh, WoTl, bo, out, nullptr, nullptr, MTOT, DD,
        nullptr, nullptr, nullptr, nullptr);
}